// Round 5
// baseline (144.661 us; speedup 1.0000x reference)
//
#include <hip/hip_runtime.h>

#define NN 512
#define DD 64
#define TOPK 20
#define BB 128

// =============== K1: ALL input-independent work in ONE launch ==================
// (byte-identical to Round-4 verified kernel)
// blocks    0..511  : ksel first (latency-bound, hides under GEMM blocks)
// blocks  512..1535 : z GEMM 64x64 tiles + zsrc/zdst epilogue
// block  1536       : es_src / es_dst + gstats zero
__global__ __launch_bounds__(256) void k1_pre(const float* __restrict__ data,
                                              const float* __restrict__ emb,
                                              const float* __restrict__ fc_w,
                                              const float* __restrict__ fc_b,
                                              const float* __restrict__ attn_w,
                                              float* __restrict__ es_src,
                                              float* __restrict__ es_dst,
                                              double* __restrict__ gstats,
                                              float* __restrict__ z,
                                              float* __restrict__ zsrc,
                                              float* __restrict__ zdst,
                                              int* __restrict__ topk) {
    __shared__ __align__(16) char smem[34816];
    const int bid = blockIdx.x, t = threadIdx.x;

    if (bid < 512) {
        // ---------------- ksel: inline cos row + norms + butterfly top-20 ------
        const int i = bid;
        double* cosrow = (double*)smem;            // 512 f64 = 4096 B
        double* nrmv   = (double*)(smem + 4096);   // 512 f64 = 4096 B
        float4* A4     = (float4*)(smem + 8192);   // emb[i] row, 256 B
        const float4* e4 = (const float4*)emb;

        if (t < 16) A4[t] = e4[i * 16 + t];
        __syncthreads();

        #pragma unroll
        for (int jj = 0; jj < 2; ++jj) {
            const int j = jj * 256 + t;
            double dot = 0.0, ss = 0.0;
            #pragma unroll
            for (int c = 0; c < 16; ++c) {
                const float4 a = A4[c];
                const float4 b = e4[j * 16 + c];
                dot += (double)a.x * (double)b.x;
                dot += (double)a.y * (double)b.y;
                dot += (double)a.z * (double)b.z;
                dot += (double)a.w * (double)b.w;
                const double vx = b.x, vy = b.y, vz = b.z, vw = b.w;
                ss += vx * vx; ss += vy * vy; ss += vz * vz; ss += vw * vw;
            }
            cosrow[j] = dot;
            nrmv[j]   = sqrt(ss);
        }
        __syncthreads();

        if (t < 64) {
            const int lane = t;
            const double nrm_i = nrmv[i];
            double v[8];
            #pragma unroll
            for (int s = 0; s < 8; ++s)
                v[s] = cosrow[s * 64 + lane] / (nrm_i * nrmv[s * 64 + lane]);

            for (int k = 0; k < TOPK; ++k) {
                double bv = v[0]; int bs = 0;
                #pragma unroll
                for (int s = 1; s < 8; ++s) if (v[s] > bv) { bv = v[s]; bs = s; }
                int bi2 = bs * 64 + lane;
                #pragma unroll
                for (int off = 32; off > 0; off >>= 1) {
                    double ov = __shfl_xor(bv, off);
                    int    oi = __shfl_xor(bi2, off);
                    if (ov > bv || (ov == bv && oi < bi2)) { bv = ov; bi2 = oi; }
                }
                if (lane == 0) topk[i * TOPK + k] = bi2;
                if ((bi2 & 63) == lane) v[bi2 >> 6] = -1e300;
            }
        }
    } else if (bid < 1536) {
        // ---------------- GEMM 64x64 tile, float4 LDS --------------------------
        float (*As)[68]  = (float(*)[68])smem;             // 17408 B
        float (*WsT)[68] = (float(*)[68])(smem + 17408);   // 17408 B
        const long r0 = (long)(bid - 512) * 64;
        const float4* data4 = (const float4*)data;
        const float4* fcw4  = (const float4*)fc_w;

        for (int m = t; m < 1024; m += 256) {
            const int r = m >> 4, c4 = m & 15;
            *(float4*)&As[r][c4 * 4] = data4[(r0 + r) * 16 + c4];
        }
        for (int m = t; m < 1024; m += 256) {
            const int d = m >> 4, f4 = m & 15;
            float4 v = fcw4[d * 16 + f4];
            WsT[f4 * 4 + 0][d] = v.x;
            WsT[f4 * 4 + 1][d] = v.y;
            WsT[f4 * 4 + 2][d] = v.z;
            WsT[f4 * 4 + 3][d] = v.w;
        }
        __syncthreads();

        const int tr = t >> 4, tc = t & 15;
        float acc[4][4] = {};
        for (int k0 = 0; k0 < 64; k0 += 4) {
            float4 a4[4], b4[4];
            #pragma unroll
            for (int i = 0; i < 4; ++i) a4[i] = *(float4*)&As[tr * 4 + i][k0];
            #pragma unroll
            for (int kk = 0; kk < 4; ++kk) b4[kk] = *(float4*)&WsT[k0 + kk][tc * 4];
            #pragma unroll
            for (int i = 0; i < 4; ++i) {
                acc[i][0] += a4[i].x * b4[0].x + a4[i].y * b4[1].x + a4[i].z * b4[2].x + a4[i].w * b4[3].x;
                acc[i][1] += a4[i].x * b4[0].y + a4[i].y * b4[1].y + a4[i].z * b4[2].y + a4[i].w * b4[3].y;
                acc[i][2] += a4[i].x * b4[0].z + a4[i].y * b4[1].z + a4[i].z * b4[2].z + a4[i].w * b4[3].z;
                acc[i][3] += a4[i].x * b4[0].w + a4[i].y * b4[1].w + a4[i].z * b4[2].w + a4[i].w * b4[3].w;
            }
        }
        float bias[4], aw0[4], aw2[4];
        #pragma unroll
        for (int j = 0; j < 4; ++j) {
            bias[j] = fc_b[tc * 4 + j];
            aw0[j]  = attn_w[tc * 4 + j];
            aw2[j]  = attn_w[128 + tc * 4 + j];
        }
        float zb[4][4];
        #pragma unroll
        for (int i = 0; i < 4; ++i) {
            #pragma unroll
            for (int j = 0; j < 4; ++j) zb[i][j] = acc[i][j] + bias[j];
            float4 vv; vv.x = zb[i][0]; vv.y = zb[i][1]; vv.z = zb[i][2]; vv.w = zb[i][3];
            *(float4*)&z[(r0 + tr * 4 + i) * 64 + tc * 4] = vv;
        }
        __syncthreads();   // all As/WsT reads done -> safe to alias

        float (*redA)[17] = (float(*)[17])smem;            // aliases As
        float (*redB)[17] = (float(*)[17])(smem + 4352);
        #pragma unroll
        for (int i = 0; i < 4; ++i) {
            redA[tr * 4 + i][tc] = zb[i][0] * aw0[0] + zb[i][1] * aw0[1] + zb[i][2] * aw0[2] + zb[i][3] * aw0[3];
            redB[tr * 4 + i][tc] = zb[i][0] * aw2[0] + zb[i][1] * aw2[1] + zb[i][2] * aw2[2] + zb[i][3] * aw2[3];
        }
        __syncthreads();
        if (t < 64) {
            float sA = 0.f, sB = 0.f;
            #pragma unroll
            for (int k = 0; k < 16; ++k) { sA += redA[t][k]; sB += redB[t][k]; }
            zsrc[r0 + t] = sA;
            zdst[r0 + t] = sB;
        }
    } else {
        // ---------------- es_src / es_dst + gstats zero ------------------------
        #pragma unroll
        for (int jj = 0; jj < 2; ++jj) {
            const int j = jj * 256 + t;
            float s1 = 0.f, s2 = 0.f;
            #pragma unroll
            for (int c = 0; c < 64; ++c) {
                const float w = emb[j * 64 + c];
                s1 += w * attn_w[64 + c];
                s2 += w * attn_w[192 + c];
            }
            es_src[j] = s1;
            es_dst[j] = s2;
        }
        if (t < 128) gstats[t] = 0.0;
    }
}

// =============== K3: own-node gather, stride-17 LDS, register softmax ==========
// Thread t owns node n = chunk*256+t end-to-end: topk indices + alphas stay in
// registers (no alf/sIdx LDS, no cross-thread handoff). zs rows padded to 17
// floats (68 B): gcd(17,32)=1 -> scalar b32 gather reads spread over all banks
// (vs 8-way conflict of the old 64 B-row b128 gather). Only 2 barriers total.
// rst values and per-element math are bit-identical to the verified kernel;
// BN partial-sum grouping changes (f64, atomic-order-tolerant).
__global__ __launch_bounds__(256) void k3_attn(const float* __restrict__ z,
                                               const float* __restrict__ zsrc,
                                               const float* __restrict__ zdst,
                                               const float* __restrict__ es_src,
                                               const float* __restrict__ es_dst,
                                               const int* __restrict__ topk,
                                               const float* __restrict__ emb,
                                               const float* __restrict__ attn_b_p,
                                               float* __restrict__ rst,
                                               double* __restrict__ gstats) {
    __shared__ __align__(16) char smem[34816];   // zs[512][17] floats / f64 BN alias
    float*  zs = (float*)smem;
    double* rr = (double*)smem;

    const int b    = blockIdx.x >> 2;
    const int dq   = blockIdx.x & 3;
    const int doff = dq * 16;
    const int t    = threadIdx.x;
    const float attn_b = *attn_b_p;
    const long b512 = (long)b * NN;

    // ---- stage z slice (dq 16 dims of all 512 nodes) at stride 17 ------------
    for (int m = t; m < 2048; m += 256) {
        const int n = m >> 2, c4i = m & 3;
        const float4 v = *(const float4*)(z + (b512 + n) * 64 + doff + c4i * 4);
        float* p = &zs[n * 17 + c4i * 4];
        p[0] = v.x; p[1] = v.y; p[2] = v.z; p[3] = v.w;
    }

    double s1[16], s2[16];
    #pragma unroll
    for (int d = 0; d < 16; ++d) { s1[d] = 0.0; s2[d] = 0.0; }

    bool synced = false;
    #pragma unroll
    for (int chunk = 0; chunk < 2; ++chunk) {
        const int n = chunk * 256 + t;

        // ---- softmax for own node (registers only; identical math/order) ------
        const float sd = zdst[b512 + n] + es_dst[n] + attn_b;
        int   idxr[TOPK];
        float ev[TOPK];
        float m0 = -1e30f;
        #pragma unroll
        for (int tt = 0; tt < TOPK; ++tt) {
            const int s = topk[n + tt * NN];   // scrambled flat edge list
            idxr[tt] = s;
            float e = zsrc[b512 + s] + es_src[s] + sd;
            e = (e >= 0.f) ? e : 0.2f * e;
            ev[tt] = e;
            m0 = fmaxf(m0, e);
        }
        float dsum = 0.f;
        #pragma unroll
        for (int tt = 0; tt < TOPK; ++tt) { ev[tt] = __expf(ev[tt] - m0); dsum += ev[tt]; }
        const float inv = 1.0f / dsum;

        if (!synced) { __syncthreads(); synced = true; }   // zs staged (hidden under softmax0)

        // ---- gather 16 dims for own node (scalar b32, conflict-light) ---------
        float acc[16];
        #pragma unroll
        for (int d = 0; d < 16; ++d) acc[d] = 0.f;
        #pragma unroll
        for (int tt = 0; tt < TOPK; ++tt) {
            const float a = ev[tt] * inv;          // same rounding as stored alpha
            const float* row = &zs[idxr[tt] * 17];
            #pragma unroll
            for (int d = 0; d < 16; ++d) acc[d] += a * row[d];
        }

        // ---- emb multiply + rst write (lane-contiguous 64 B) + BN partials ----
        const float* eb = &emb[n * 64 + doff];
        float r[16];
        #pragma unroll
        for (int d = 0; d < 16; ++d) {
            r[d] = acc[d] * eb[d];
            s1[d] += (double)r[d];
            s2[d] += (double)r[d] * (double)r[d];
        }
        float* ro = &rst[(b512 + n) * 64 + doff];
        #pragma unroll
        for (int q = 0; q < 4; ++q) {
            float4 vv; vv.x = r[q*4+0]; vv.y = r[q*4+1]; vv.z = r[q*4+2]; vv.w = r[q*4+3];
            *(float4*)&ro[q * 4] = vv;
        }
    }

    // ---- BN reduce: two passes through zs-aliased f64 scratch -----------------
    __syncthreads();   // all gather reads of zs done -> safe to alias
    #pragma unroll
    for (int d = 0; d < 16; ++d) rr[d * 256 + t] = s1[d];
    __syncthreads();
    if (t < 16) {
        double a = 0.0;
        for (int q = 0; q < 256; ++q) a += rr[t * 256 + q];
        atomicAdd(&gstats[doff + t], a);
    }
    __syncthreads();
    #pragma unroll
    for (int d = 0; d < 16; ++d) rr[d * 256 + t] = s2[d];
    __syncthreads();
    if (t < 16) {
        double a = 0.0;
        for (int q = 0; q < 256; ++q) a += rr[t * 256 + q];
        atomicAdd(&gstats[64 + doff + t], a);
    }
}

// =============== K5: BN finalize (per-block) + apply + ReLU + out_w dot ========
// (byte-identical to the verified kernel)
__global__ __launch_bounds__(256) void k5_out(const float* __restrict__ rst,
                                              const double* __restrict__ gstats,
                                              const float* __restrict__ gamma,
                                              const float* __restrict__ beta,
                                              const float* __restrict__ out_w,
                                              const float* __restrict__ out_b_p,
                                              float* __restrict__ out) {
    __shared__ float scv[64], biv[64];
    const int t = threadIdx.x;
    if (t < 64) {
        const double M = (double)BB * (double)NN;
        const double s  = gstats[t];
        const double s2 = gstats[64 + t];
        const double mu  = s / M;
        const double var = s2 / M - mu * mu;
        const float scale = (float)((double)gamma[t] / sqrt(var + 1e-5));
        scv[t] = scale;
        biv[t] = beta[t] - (float)mu * scale;
    }
    __syncthreads();

    const int wid = t >> 6, lane = t & 63;
    const float sc = scv[lane], bi = biv[lane], ow = out_w[lane];
    const float ob = *out_b_p;
    const long rowbase = (long)blockIdx.x * 16 + wid * 4;
    float v[4];
    #pragma unroll
    for (int rr = 0; rr < 4; ++rr)
        v[rr] = fmaxf(rst[(rowbase + rr) * 64 + lane] * sc + bi, 0.f) * ow;
    #pragma unroll
    for (int off = 32; off > 0; off >>= 1)
        #pragma unroll
        for (int rr = 0; rr < 4; ++rr) v[rr] += __shfl_down(v[rr], off);
    if (lane == 0)
        #pragma unroll
        for (int rr = 0; rr < 4; ++rr) out[rowbase + rr] = v[rr] + ob;
}

extern "C" void kernel_launch(void* const* d_in, const int* in_sizes, int n_in,
                              void* d_out, int out_size, void* d_ws, size_t ws_size,
                              hipStream_t stream) {
    const float* data   = (const float*)d_in[0];
    const float* emb    = (const float*)d_in[1];
    const float* fc_w   = (const float*)d_in[2];
    const float* fc_b   = (const float*)d_in[3];
    const float* attn_w = (const float*)d_in[4];
    const float* attn_b = (const float*)d_in[5];
    const float* gamma  = (const float*)d_in[6];
    const float* beta   = (const float*)d_in[7];
    const float* out_w  = (const float*)d_in[8];
    const float* out_b  = (const float*)d_in[9];
    float* out = (float*)d_out;

    char* ws = (char*)d_ws;
    float*  z      = (float*) (ws + 0);            // 16 MB
    float*  rst    = (float*) (ws + 16777216);     // 16 MB
    float*  zsrc   = (float*) (ws + 33554432);     // 256 KB
    float*  zdst   = (float*) (ws + 33816576);     // 256 KB
    int*    topk   = (int*)   (ws + 34078720);     // 40 KB
    float*  es_src = (float*) (ws + 34119680);     // 2 KB
    float*  es_dst = (float*) (ws + 34121728);     // 2 KB
    double* gstats = (double*)(ws + 34123776);     // 1 KB

    k1_pre<<<1537, 256, 0, stream>>>(data, emb, fc_w, fc_b, attn_w,
                                     es_src, es_dst, gstats,
                                     z, zsrc, zdst, topk);
    k3_attn<<<BB * 4, 256, 0, stream>>>(z, zsrc, zdst, es_src, es_dst, topk, emb,
                                        attn_b, rst, gstats);
    k5_out<<<4096, 256, 0, stream>>>(rst, gstats, gamma, beta, out_w, out_b, out);
}

// Round 6
// 141.726 us; speedup vs baseline: 1.0207x; 1.0207x over previous
//
#include <hip/hip_runtime.h>

#define NN 512
#define DD 64
#define TOPK 20
#define BB 128

// =============== K1: ALL input-independent work in ONE launch ==================
// blocks    0..127  : ksel, 4 nodes/block (one per wave) — norms computed ONCE
//                     per block; all 4 waves run selection butterflies
//                     concurrently. Dispatched first so the latency chains hide
//                     under the GEMM blocks that follow.
// blocks  128..1151 : z GEMM 64x64 tiles + zsrc/zdst epilogue (bit-identical)
// block  1152       : es_src / es_dst + gstats zero
__global__ __launch_bounds__(256) void k1_pre(const float* __restrict__ data,
                                              const float* __restrict__ emb,
                                              const float* __restrict__ fc_w,
                                              const float* __restrict__ fc_b,
                                              const float* __restrict__ attn_w,
                                              float* __restrict__ es_src,
                                              float* __restrict__ es_dst,
                                              double* __restrict__ gstats,
                                              float* __restrict__ z,
                                              float* __restrict__ zsrc,
                                              float* __restrict__ zdst,
                                              int* __restrict__ topk) {
    __shared__ __align__(16) char smem[34816];
    const int bid = blockIdx.x, t = threadIdx.x;

    if (bid < 128) {
        // ---------------- ksel: 4 nodes/block, butterfly top-20 per wave -------
        double* cosrow = (double*)smem;            // [4][512] f64 = 16384 B
        double* nrmv   = (double*)(smem + 16384);  // [512] f64  =  4096 B
        float4* A4     = (float4*)(smem + 20480);  // [4][16] f4 =  1024 B
        const float4* e4 = (const float4*)emb;
        const int i0 = bid * 4;

        if (t < 64) A4[t] = e4[i0 * 16 + t];       // 4 emb rows

        // norms once per block (identical per-norm summation order)
        #pragma unroll
        for (int jj = 0; jj < 2; ++jj) {
            const int j = jj * 256 + t;
            double ss = 0.0;
            #pragma unroll
            for (int c = 0; c < 16; ++c) {
                const float4 b = e4[j * 16 + c];
                const double vx = b.x, vy = b.y, vz = b.z, vw = b.w;
                ss += vx * vx; ss += vy * vy; ss += vz * vz; ss += vw * vw;
            }
            nrmv[j] = sqrt(ss);
        }
        __syncthreads();   // A4 + nrmv visible to all waves

        const int w = t >> 6, lane = t & 63;
        const int i = i0 + w;
        const float4* Arow = &A4[w * 16];
        double* crow = &cosrow[w * 512];

        // own node's dot row (identical per-dot summation order)
        #pragma unroll
        for (int q = 0; q < 8; ++q) {
            const int j = q * 64 + lane;
            double dot = 0.0;
            #pragma unroll
            for (int c = 0; c < 16; ++c) {
                const float4 a = Arow[c];
                const float4 b = e4[j * 16 + c];
                dot += (double)a.x * (double)b.x;
                dot += (double)a.y * (double)b.y;
                dot += (double)a.z * (double)b.z;
                dot += (double)a.w * (double)b.w;
            }
            crow[j] = dot;
        }
        // within-wave write->read: no barrier needed (waitcnt handled by compiler)

        const double nrm_i = nrmv[i];
        double v[8];
        #pragma unroll
        for (int s = 0; s < 8; ++s)
            v[s] = crow[s * 64 + lane] / (nrm_i * nrmv[s * 64 + lane]);

        for (int k = 0; k < TOPK; ++k) {
            double bv = v[0]; int bs = 0;
            #pragma unroll
            for (int s = 1; s < 8; ++s) if (v[s] > bv) { bv = v[s]; bs = s; }
            int bi2 = bs * 64 + lane;
            #pragma unroll
            for (int off = 32; off > 0; off >>= 1) {
                double ov = __shfl_xor(bv, off);
                int    oi = __shfl_xor(bi2, off);
                if (ov > bv || (ov == bv && oi < bi2)) { bv = ov; bi2 = oi; }
            }
            if (lane == 0) topk[i * TOPK + k] = bi2;
            if ((bi2 & 63) == lane) v[bi2 >> 6] = -1e300;
        }
    } else if (bid < 1152) {
        // ---------------- GEMM 64x64 tile, float4 LDS (bit-identical) ----------
        float (*As)[68]  = (float(*)[68])smem;             // 17408 B
        float (*WsT)[68] = (float(*)[68])(smem + 17408);   // 17408 B
        const long r0 = (long)(bid - 128) * 64;
        const float4* data4 = (const float4*)data;
        const float4* fcw4  = (const float4*)fc_w;

        for (int m = t; m < 1024; m += 256) {
            const int r = m >> 4, c4 = m & 15;
            *(float4*)&As[r][c4 * 4] = data4[(r0 + r) * 16 + c4];
        }
        for (int m = t; m < 1024; m += 256) {
            const int d = m >> 4, f4 = m & 15;
            float4 v = fcw4[d * 16 + f4];
            WsT[f4 * 4 + 0][d] = v.x;
            WsT[f4 * 4 + 1][d] = v.y;
            WsT[f4 * 4 + 2][d] = v.z;
            WsT[f4 * 4 + 3][d] = v.w;
        }
        __syncthreads();

        const int tr = t >> 4, tc = t & 15;
        float acc[4][4] = {};
        for (int k0 = 0; k0 < 64; k0 += 4) {
            float4 a4[4], b4[4];
            #pragma unroll
            for (int i = 0; i < 4; ++i) a4[i] = *(float4*)&As[tr * 4 + i][k0];
            #pragma unroll
            for (int kk = 0; kk < 4; ++kk) b4[kk] = *(float4*)&WsT[k0 + kk][tc * 4];
            #pragma unroll
            for (int i = 0; i < 4; ++i) {
                acc[i][0] += a4[i].x * b4[0].x + a4[i].y * b4[1].x + a4[i].z * b4[2].x + a4[i].w * b4[3].x;
                acc[i][1] += a4[i].x * b4[0].y + a4[i].y * b4[1].y + a4[i].z * b4[2].y + a4[i].w * b4[3].y;
                acc[i][2] += a4[i].x * b4[0].z + a4[i].y * b4[1].z + a4[i].z * b4[2].z + a4[i].w * b4[3].z;
                acc[i][3] += a4[i].x * b4[0].w + a4[i].y * b4[1].w + a4[i].z * b4[2].w + a4[i].w * b4[3].w;
            }
        }
        float bias[4], aw0[4], aw2[4];
        #pragma unroll
        for (int j = 0; j < 4; ++j) {
            bias[j] = fc_b[tc * 4 + j];
            aw0[j]  = attn_w[tc * 4 + j];
            aw2[j]  = attn_w[128 + tc * 4 + j];
        }
        float zb[4][4];
        #pragma unroll
        for (int i = 0; i < 4; ++i) {
            #pragma unroll
            for (int j = 0; j < 4; ++j) zb[i][j] = acc[i][j] + bias[j];
            float4 vv; vv.x = zb[i][0]; vv.y = zb[i][1]; vv.z = zb[i][2]; vv.w = zb[i][3];
            *(float4*)&z[(r0 + tr * 4 + i) * 64 + tc * 4] = vv;
        }
        __syncthreads();   // all As/WsT reads done -> safe to alias

        float (*redA)[17] = (float(*)[17])smem;            // aliases As
        float (*redB)[17] = (float(*)[17])(smem + 4352);
        #pragma unroll
        for (int i = 0; i < 4; ++i) {
            redA[tr * 4 + i][tc] = zb[i][0] * aw0[0] + zb[i][1] * aw0[1] + zb[i][2] * aw0[2] + zb[i][3] * aw0[3];
            redB[tr * 4 + i][tc] = zb[i][0] * aw2[0] + zb[i][1] * aw2[1] + zb[i][2] * aw2[2] + zb[i][3] * aw2[3];
        }
        __syncthreads();
        if (t < 64) {
            float sA = 0.f, sB = 0.f;
            #pragma unroll
            for (int k = 0; k < 16; ++k) { sA += redA[t][k]; sB += redB[t][k]; }
            zsrc[r0 + t] = sA;
            zdst[r0 + t] = sB;
        }
    } else {
        // ---------------- es_src / es_dst + gstats zero ------------------------
        #pragma unroll
        for (int jj = 0; jj < 2; ++jj) {
            const int j = jj * 256 + t;
            float s1 = 0.f, s2 = 0.f;
            #pragma unroll
            for (int c = 0; c < 64; ++c) {
                const float w = emb[j * 64 + c];
                s1 += w * attn_w[64 + c];
                s2 += w * attn_w[192 + c];
            }
            es_src[j] = s1;
            es_dst[j] = s2;
        }
        if (t < 128) gstats[t] = 0.0;
    }
}

// =============== K3: verified R0 structure, zs rows padded to 80 B =============
// Identical instruction stream to the verified kernel; only the zs row stride
// changes 16 -> 20 floats. Row start bank-quad = 5*idx mod 8 (uniform over all
// 8 quads for random idx) vs 2 quads at 64 B rows -> breaks the ~8-way LDS
// bank conflict on the random-row b128 gather. LDS 70 KB -> still 2 blocks/CU.
__global__ __launch_bounds__(256) void k3_attn(const float* __restrict__ z,
                                               const float* __restrict__ zsrc,
                                               const float* __restrict__ zdst,
                                               const float* __restrict__ es_src,
                                               const float* __restrict__ es_dst,
                                               const int* __restrict__ topk,
                                               const float* __restrict__ emb,
                                               const float* __restrict__ attn_b_p,
                                               float* __restrict__ rst,
                                               double* __restrict__ gstats) {
    __shared__ float  zs[512 * 20];          // 40 KB (rows: 5 float4, slot 4 = pad)
    __shared__ double alf_pool[2560];        // 20 KB: alpha[256][20] / BN-reduce alias
    __shared__ unsigned short sIdx[256 * 20];// 10 KB
    float* alf = (float*)alf_pool;
    const float4* alf4 = (const float4*)alf_pool;   // rows are 80 B = 5 float4

    const int b    = blockIdx.x >> 2;
    const int dq   = blockIdx.x & 3;
    const int doff = dq * 16;
    const int t    = threadIdx.x;
    const float attn_b = *attn_b_p;
    const long b512 = (long)b * NN;

    float4* zs4 = (float4*)zs;
    for (int m = t; m < 2048; m += 256) {
        const int n = m >> 2, c4i = m & 3;
        zs4[n * 5 + c4i] = *(const float4*)(z + (b512 + n) * 64 + doff + c4i * 4);
    }
    __syncthreads();

    const int c4 = t & 3;
    const int rq = t >> 2;
    double s1[4] = {0,0,0,0}, s2[4] = {0,0,0,0};

    for (int chunk = 0; chunk < 2; ++chunk) {
        {
            const int n = chunk * 256 + t;
            const float sd = zdst[b512 + n] + es_dst[n] + attn_b;
            float ev[TOPK];
            float m0 = -1e30f;
            #pragma unroll
            for (int tt = 0; tt < TOPK; ++tt) {
                const int s = topk[n + tt * NN];   // scrambled flat edge list
                sIdx[t * TOPK + tt] = (unsigned short)s;
                float e = zsrc[b512 + s] + es_src[s] + sd;
                e = (e >= 0.f) ? e : 0.2f * e;
                ev[tt] = e;
                m0 = fmaxf(m0, e);
            }
            float dsum = 0.f;
            #pragma unroll
            for (int tt = 0; tt < TOPK; ++tt) { ev[tt] = __expf(ev[tt] - m0); dsum += ev[tt]; }
            const float inv = 1.0f / dsum;
            #pragma unroll
            for (int tt = 0; tt < TOPK; ++tt) alf[t * TOPK + tt] = ev[tt] * inv;
        }
        __syncthreads();

        #pragma unroll
        for (int it = 0; it < 4; ++it) {
            const int nl = it * 64 + rq;
            const int n  = chunk * 256 + nl;
            float4 af[5];
            #pragma unroll
            for (int q = 0; q < 5; ++q) af[q] = alf4[nl * 5 + q];
            const float* av = (const float*)af;
            float4 acc = {0.f, 0.f, 0.f, 0.f};
            #pragma unroll
            for (int tt = 0; tt < TOPK; ++tt) {
                const float a = av[tt];
                const float4 zv = zs4[(int)sIdx[nl * TOPK + tt] * 5 + c4];
                acc.x += a * zv.x; acc.y += a * zv.y; acc.z += a * zv.z; acc.w += a * zv.w;
            }
            const float4 ev = *(const float4*)&emb[n * 64 + doff + c4 * 4];
            float4 r;
            r.x = acc.x * ev.x; r.y = acc.y * ev.y; r.z = acc.z * ev.z; r.w = acc.w * ev.w;
            *(float4*)&rst[(b512 + n) * 64 + doff + c4 * 4] = r;
            s1[0] += (double)r.x; s2[0] += (double)r.x * (double)r.x;
            s1[1] += (double)r.y; s2[1] += (double)r.y * (double)r.y;
            s1[2] += (double)r.z; s2[2] += (double)r.z * (double)r.z;
            s1[3] += (double)r.w; s2[3] += (double)r.w * (double)r.w;
        }
        __syncthreads();
    }

    double* r1 = alf_pool;
    double* r2 = alf_pool + 1024;
    #pragma unroll
    for (int j = 0; j < 4; ++j) {
        r1[(c4 * 4 + j) * 64 + rq] = s1[j];
        r2[(c4 * 4 + j) * 64 + rq] = s2[j];
    }
    __syncthreads();
    if (t < 16) {
        double a = 0.0, bb = 0.0;
        for (int q = 0; q < 64; ++q) { a += r1[t * 64 + q]; bb += r2[t * 64 + q]; }
        atomicAdd(&gstats[doff + t], a);
        atomicAdd(&gstats[64 + doff + t], bb);
    }
}

// =============== K5: BN finalize (per-block) + apply + ReLU + out_w dot ========
// (byte-identical to the verified kernel)
__global__ __launch_bounds__(256) void k5_out(const float* __restrict__ rst,
                                              const double* __restrict__ gstats,
                                              const float* __restrict__ gamma,
                                              const float* __restrict__ beta,
                                              const float* __restrict__ out_w,
                                              const float* __restrict__ out_b_p,
                                              float* __restrict__ out) {
    __shared__ float scv[64], biv[64];
    const int t = threadIdx.x;
    if (t < 64) {
        const double M = (double)BB * (double)NN;
        const double s  = gstats[t];
        const double s2 = gstats[64 + t];
        const double mu  = s / M;
        const double var = s2 / M - mu * mu;
        const float scale = (float)((double)gamma[t] / sqrt(var + 1e-5));
        scv[t] = scale;
        biv[t] = beta[t] - (float)mu * scale;
    }
    __syncthreads();

    const int wid = t >> 6, lane = t & 63;
    const float sc = scv[lane], bi = biv[lane], ow = out_w[lane];
    const float ob = *out_b_p;
    const long rowbase = (long)blockIdx.x * 16 + wid * 4;
    float v[4];
    #pragma unroll
    for (int rr = 0; rr < 4; ++rr)
        v[rr] = fmaxf(rst[(rowbase + rr) * 64 + lane] * sc + bi, 0.f) * ow;
    #pragma unroll
    for (int off = 32; off > 0; off >>= 1)
        #pragma unroll
        for (int rr = 0; rr < 4; ++rr) v[rr] += __shfl_down(v[rr], off);
    if (lane == 0)
        #pragma unroll
        for (int rr = 0; rr < 4; ++rr) out[rowbase + rr] = v[rr] + ob;
}

extern "C" void kernel_launch(void* const* d_in, const int* in_sizes, int n_in,
                              void* d_out, int out_size, void* d_ws, size_t ws_size,
                              hipStream_t stream) {
    const float* data   = (const float*)d_in[0];
    const float* emb    = (const float*)d_in[1];
    const float* fc_w   = (const float*)d_in[2];
    const float* fc_b   = (const float*)d_in[3];
    const float* attn_w = (const float*)d_in[4];
    const float* attn_b = (const float*)d_in[5];
    const float* gamma  = (const float*)d_in[6];
    const float* beta   = (const float*)d_in[7];
    const float* out_w  = (const float*)d_in[8];
    const float* out_b  = (const float*)d_in[9];
    float* out = (float*)d_out;

    char* ws = (char*)d_ws;
    float*  z      = (float*) (ws + 0);            // 16 MB
    float*  rst    = (float*) (ws + 16777216);     // 16 MB
    float*  zsrc   = (float*) (ws + 33554432);     // 256 KB
    float*  zdst   = (float*) (ws + 33816576);     // 256 KB
    int*    topk   = (int*)   (ws + 34078720);     // 40 KB
    float*  es_src = (float*) (ws + 34119680);     // 2 KB
    float*  es_dst = (float*) (ws + 34121728);     // 2 KB
    double* gstats = (double*)(ws + 34123776);     // 1 KB

    k1_pre<<<1153, 256, 0, stream>>>(data, emb, fc_w, fc_b, attn_w,
                                     es_src, es_dst, gstats,
                                     z, zsrc, zdst, topk);
    k3_attn<<<BB * 4, 256, 0, stream>>>(z, zsrc, zdst, es_src, es_dst, topk, emb,
                                        attn_b, rst, gstats);
    k5_out<<<4096, 256, 0, stream>>>(rst, gstats, gamma, beta, out_w, out_b, out);
}

// Round 7
// 135.946 us; speedup vs baseline: 1.0641x; 1.0425x over previous
//
#include <hip/hip_runtime.h>

#define NN 512
#define DD 64
#define TOPK 20
#define BB 128

// =============== K1: ALL input-independent work in ONE launch ==================
// blocks    0..511  : ksel first (latency-bound, hides under GEMM blocks).
//                     NOTE: eviction uses STATIC-indexed cndmask writes — the
//                     previous `v[bi2>>6] = -1e300` runtime index forced v[8]
//                     into scratch (HBM round-trips on the serial chain).
// blocks  512..1535 : z GEMM 64x64 tiles + zsrc/zdst epilogue (bit-identical)
// block  1536       : es_src / es_dst + gstats zero
__global__ __launch_bounds__(256) void k1_pre(const float* __restrict__ data,
                                              const float* __restrict__ emb,
                                              const float* __restrict__ fc_w,
                                              const float* __restrict__ fc_b,
                                              const float* __restrict__ attn_w,
                                              float* __restrict__ es_src,
                                              float* __restrict__ es_dst,
                                              double* __restrict__ gstats,
                                              float* __restrict__ z,
                                              float* __restrict__ zsrc,
                                              float* __restrict__ zdst,
                                              int* __restrict__ topk) {
    __shared__ __align__(16) char smem[34816];
    const int bid = blockIdx.x, t = threadIdx.x;

    if (bid < 512) {
        // ---------------- ksel: inline cos row + norms + butterfly top-20 ------
        const int i = bid;
        double* cosrow = (double*)smem;            // 512 f64 = 4096 B
        double* nrmv   = (double*)(smem + 4096);   // 512 f64 = 4096 B
        float4* A4     = (float4*)(smem + 8192);   // emb[i] row, 256 B
        const float4* e4 = (const float4*)emb;

        if (t < 16) A4[t] = e4[i * 16 + t];
        __syncthreads();

        #pragma unroll
        for (int jj = 0; jj < 2; ++jj) {
            const int j = jj * 256 + t;
            double dot = 0.0, ss = 0.0;
            #pragma unroll
            for (int c = 0; c < 16; ++c) {
                const float4 a = A4[c];
                const float4 b = e4[j * 16 + c];
                dot += (double)a.x * (double)b.x;
                dot += (double)a.y * (double)b.y;
                dot += (double)a.z * (double)b.z;
                dot += (double)a.w * (double)b.w;
                const double vx = b.x, vy = b.y, vz = b.z, vw = b.w;
                ss += vx * vx; ss += vy * vy; ss += vz * vz; ss += vw * vw;
            }
            cosrow[j] = dot;
            nrmv[j]   = sqrt(ss);
        }
        __syncthreads();

        if (t < 64) {
            const int lane = t;
            const double nrm_i = nrmv[i];
            double v[8];
            #pragma unroll
            for (int s = 0; s < 8; ++s)
                v[s] = cosrow[s * 64 + lane] / (nrm_i * nrmv[s * 64 + lane]);

            for (int k = 0; k < TOPK; ++k) {
                double bv = v[0]; int bs = 0;
                #pragma unroll
                for (int s = 1; s < 8; ++s) if (v[s] > bv) { bv = v[s]; bs = s; }
                int bi2 = bs * 64 + lane;
                #pragma unroll
                for (int off = 32; off > 0; off >>= 1) {
                    double ov = __shfl_xor(bv, off);
                    int    oi = __shfl_xor(bi2, off);
                    if (ov > bv || (ov == bv && oi < bi2)) { bv = ov; bi2 = oi; }
                }
                if (lane == 0) topk[i * TOPK + k] = bi2;
                // STATIC-indexed eviction (keeps v[] in VGPRs; semantics identical)
                const int  vsel = bi2 >> 6;
                const bool hit  = (bi2 & 63) == lane;
                #pragma unroll
                for (int s = 0; s < 8; ++s)
                    v[s] = (hit && vsel == s) ? -1e300 : v[s];
            }
        }
    } else if (bid < 1536) {
        // ---------------- GEMM 64x64 tile, float4 LDS (bit-identical) ----------
        float (*As)[68]  = (float(*)[68])smem;             // 17408 B
        float (*WsT)[68] = (float(*)[68])(smem + 17408);   // 17408 B
        const long r0 = (long)(bid - 512) * 64;
        const float4* data4 = (const float4*)data;
        const float4* fcw4  = (const float4*)fc_w;

        for (int m = t; m < 1024; m += 256) {
            const int r = m >> 4, c4 = m & 15;
            *(float4*)&As[r][c4 * 4] = data4[(r0 + r) * 16 + c4];
        }
        for (int m = t; m < 1024; m += 256) {
            const int d = m >> 4, f4 = m & 15;
            float4 v = fcw4[d * 16 + f4];
            WsT[f4 * 4 + 0][d] = v.x;
            WsT[f4 * 4 + 1][d] = v.y;
            WsT[f4 * 4 + 2][d] = v.z;
            WsT[f4 * 4 + 3][d] = v.w;
        }
        __syncthreads();

        const int tr = t >> 4, tc = t & 15;
        float acc[4][4] = {};
        for (int k0 = 0; k0 < 64; k0 += 4) {
            float4 a4[4], b4[4];
            #pragma unroll
            for (int i = 0; i < 4; ++i) a4[i] = *(float4*)&As[tr * 4 + i][k0];
            #pragma unroll
            for (int kk = 0; kk < 4; ++kk) b4[kk] = *(float4*)&WsT[k0 + kk][tc * 4];
            #pragma unroll
            for (int i = 0; i < 4; ++i) {
                acc[i][0] += a4[i].x * b4[0].x + a4[i].y * b4[1].x + a4[i].z * b4[2].x + a4[i].w * b4[3].x;
                acc[i][1] += a4[i].x * b4[0].y + a4[i].y * b4[1].y + a4[i].z * b4[2].y + a4[i].w * b4[3].y;
                acc[i][2] += a4[i].x * b4[0].z + a4[i].y * b4[1].z + a4[i].z * b4[2].z + a4[i].w * b4[3].z;
                acc[i][3] += a4[i].x * b4[0].w + a4[i].y * b4[1].w + a4[i].z * b4[2].w + a4[i].w * b4[3].w;
            }
        }
        float bias[4], aw0[4], aw2[4];
        #pragma unroll
        for (int j = 0; j < 4; ++j) {
            bias[j] = fc_b[tc * 4 + j];
            aw0[j]  = attn_w[tc * 4 + j];
            aw2[j]  = attn_w[128 + tc * 4 + j];
        }
        float zb[4][4];
        #pragma unroll
        for (int i = 0; i < 4; ++i) {
            #pragma unroll
            for (int j = 0; j < 4; ++j) zb[i][j] = acc[i][j] + bias[j];
            float4 vv; vv.x = zb[i][0]; vv.y = zb[i][1]; vv.z = zb[i][2]; vv.w = zb[i][3];
            *(float4*)&z[(r0 + tr * 4 + i) * 64 + tc * 4] = vv;
        }
        __syncthreads();   // all As/WsT reads done -> safe to alias

        float (*redA)[17] = (float(*)[17])smem;            // aliases As
        float (*redB)[17] = (float(*)[17])(smem + 4352);
        #pragma unroll
        for (int i = 0; i < 4; ++i) {
            redA[tr * 4 + i][tc] = zb[i][0] * aw0[0] + zb[i][1] * aw0[1] + zb[i][2] * aw0[2] + zb[i][3] * aw0[3];
            redB[tr * 4 + i][tc] = zb[i][0] * aw2[0] + zb[i][1] * aw2[1] + zb[i][2] * aw2[2] + zb[i][3] * aw2[3];
        }
        __syncthreads();
        if (t < 64) {
            float sA = 0.f, sB = 0.f;
            #pragma unroll
            for (int k = 0; k < 16; ++k) { sA += redA[t][k]; sB += redB[t][k]; }
            zsrc[r0 + t] = sA;
            zdst[r0 + t] = sB;
        }
    } else {
        // ---------------- es_src / es_dst + gstats zero ------------------------
        #pragma unroll
        for (int jj = 0; jj < 2; ++jj) {
            const int j = jj * 256 + t;
            float s1 = 0.f, s2 = 0.f;
            #pragma unroll
            for (int c = 0; c < 64; ++c) {
                const float w = emb[j * 64 + c];
                s1 += w * attn_w[64 + c];
                s2 += w * attn_w[192 + c];
            }
            es_src[j] = s1;
            es_dst[j] = s2;
        }
        if (t < 128) gstats[t] = 0.0;
    }
}

// =============== K3: verified structure, zs rows padded to 80 B ================
// Identical instruction stream to the verified kernel; only the zs row stride
// is 20 floats. Row start bank-quad = 5*idx mod 8 -> random rows spread over
// all 8 quads (vs 2 at 64 B rows) on the b128 gather. LDS 70 KB -> 2 blocks/CU.
__global__ __launch_bounds__(256) void k3_attn(const float* __restrict__ z,
                                               const float* __restrict__ zsrc,
                                               const float* __restrict__ zdst,
                                               const float* __restrict__ es_src,
                                               const float* __restrict__ es_dst,
                                               const int* __restrict__ topk,
                                               const float* __restrict__ emb,
                                               const float* __restrict__ attn_b_p,
                                               float* __restrict__ rst,
                                               double* __restrict__ gstats) {
    __shared__ float  zs[512 * 20];          // 40 KB (rows: 5 float4, slot 4 = pad)
    __shared__ double alf_pool[2560];        // 20 KB: alpha[256][20] / BN-reduce alias
    __shared__ unsigned short sIdx[256 * 20];// 10 KB
    float* alf = (float*)alf_pool;
    const float4* alf4 = (const float4*)alf_pool;   // rows are 80 B = 5 float4

    const int b    = blockIdx.x >> 2;
    const int dq   = blockIdx.x & 3;
    const int doff = dq * 16;
    const int t    = threadIdx.x;
    const float attn_b = *attn_b_p;
    const long b512 = (long)b * NN;

    float4* zs4 = (float4*)zs;
    for (int m = t; m < 2048; m += 256) {
        const int n = m >> 2, c4i = m & 3;
        zs4[n * 5 + c4i] = *(const float4*)(z + (b512 + n) * 64 + doff + c4i * 4);
    }
    __syncthreads();

    const int c4 = t & 3;
    const int rq = t >> 2;
    double s1[4] = {0,0,0,0}, s2[4] = {0,0,0,0};

    for (int chunk = 0; chunk < 2; ++chunk) {
        {
            const int n = chunk * 256 + t;
            const float sd = zdst[b512 + n] + es_dst[n] + attn_b;
            float ev[TOPK];
            float m0 = -1e30f;
            #pragma unroll
            for (int tt = 0; tt < TOPK; ++tt) {
                const int s = topk[n + tt * NN];   // scrambled flat edge list
                sIdx[t * TOPK + tt] = (unsigned short)s;
                float e = zsrc[b512 + s] + es_src[s] + sd;
                e = (e >= 0.f) ? e : 0.2f * e;
                ev[tt] = e;
                m0 = fmaxf(m0, e);
            }
            float dsum = 0.f;
            #pragma unroll
            for (int tt = 0; tt < TOPK; ++tt) { ev[tt] = __expf(ev[tt] - m0); dsum += ev[tt]; }
            const float inv = 1.0f / dsum;
            #pragma unroll
            for (int tt = 0; tt < TOPK; ++tt) alf[t * TOPK + tt] = ev[tt] * inv;
        }
        __syncthreads();

        #pragma unroll
        for (int it = 0; it < 4; ++it) {
            const int nl = it * 64 + rq;
            const int n  = chunk * 256 + nl;
            float4 af[5];
            #pragma unroll
            for (int q = 0; q < 5; ++q) af[q] = alf4[nl * 5 + q];
            const float* av = (const float*)af;
            float4 acc = {0.f, 0.f, 0.f, 0.f};
            #pragma unroll
            for (int tt = 0; tt < TOPK; ++tt) {
                const float a = av[tt];
                const float4 zv = zs4[(int)sIdx[nl * TOPK + tt] * 5 + c4];
                acc.x += a * zv.x; acc.y += a * zv.y; acc.z += a * zv.z; acc.w += a * zv.w;
            }
            const float4 ev = *(const float4*)&emb[n * 64 + doff + c4 * 4];
            float4 r;
            r.x = acc.x * ev.x; r.y = acc.y * ev.y; r.z = acc.z * ev.z; r.w = acc.w * ev.w;
            *(float4*)&rst[(b512 + n) * 64 + doff + c4 * 4] = r;
            s1[0] += (double)r.x; s2[0] += (double)r.x * (double)r.x;
            s1[1] += (double)r.y; s2[1] += (double)r.y * (double)r.y;
            s1[2] += (double)r.z; s2[2] += (double)r.z * (double)r.z;
            s1[3] += (double)r.w; s2[3] += (double)r.w * (double)r.w;
        }
        __syncthreads();
    }

    double* r1 = alf_pool;
    double* r2 = alf_pool + 1024;
    #pragma unroll
    for (int j = 0; j < 4; ++j) {
        r1[(c4 * 4 + j) * 64 + rq] = s1[j];
        r2[(c4 * 4 + j) * 64 + rq] = s2[j];
    }
    __syncthreads();
    if (t < 16) {
        double a = 0.0, bb = 0.0;
        for (int q = 0; q < 64; ++q) { a += r1[t * 64 + q]; bb += r2[t * 64 + q]; }
        atomicAdd(&gstats[doff + t], a);
        atomicAdd(&gstats[64 + doff + t], bb);
    }
}

// =============== K5: BN finalize (per-block) + apply + ReLU + out_w dot ========
// (byte-identical to the verified kernel)
__global__ __launch_bounds__(256) void k5_out(const float* __restrict__ rst,
                                              const double* __restrict__ gstats,
                                              const float* __restrict__ gamma,
                                              const float* __restrict__ beta,
                                              const float* __restrict__ out_w,
                                              const float* __restrict__ out_b_p,
                                              float* __restrict__ out) {
    __shared__ float scv[64], biv[64];
    const int t = threadIdx.x;
    if (t < 64) {
        const double M = (double)BB * (double)NN;
        const double s  = gstats[t];
        const double s2 = gstats[64 + t];
        const double mu  = s / M;
        const double var = s2 / M - mu * mu;
        const float scale = (float)((double)gamma[t] / sqrt(var + 1e-5));
        scv[t] = scale;
        biv[t] = beta[t] - (float)mu * scale;
    }
    __syncthreads();

    const int wid = t >> 6, lane = t & 63;
    const float sc = scv[lane], bi = biv[lane], ow = out_w[lane];
    const float ob = *out_b_p;
    const long rowbase = (long)blockIdx.x * 16 + wid * 4;
    float v[4];
    #pragma unroll
    for (int rr = 0; rr < 4; ++rr)
        v[rr] = fmaxf(rst[(rowbase + rr) * 64 + lane] * sc + bi, 0.f) * ow;
    #pragma unroll
    for (int off = 32; off > 0; off >>= 1)
        #pragma unroll
        for (int rr = 0; rr < 4; ++rr) v[rr] += __shfl_down(v[rr], off);
    if (lane == 0)
        #pragma unroll
        for (int rr = 0; rr < 4; ++rr) out[rowbase + rr] = v[rr] + ob;
}

extern "C" void kernel_launch(void* const* d_in, const int* in_sizes, int n_in,
                              void* d_out, int out_size, void* d_ws, size_t ws_size,
                              hipStream_t stream) {
    const float* data   = (const float*)d_in[0];
    const float* emb    = (const float*)d_in[1];
    const float* fc_w   = (const float*)d_in[2];
    const float* fc_b   = (const float*)d_in[3];
    const float* attn_w = (const float*)d_in[4];
    const float* attn_b = (const float*)d_in[5];
    const float* gamma  = (const float*)d_in[6];
    const float* beta   = (const float*)d_in[7];
    const float* out_w  = (const float*)d_in[8];
    const float* out_b  = (const float*)d_in[9];
    float* out = (float*)d_out;

    char* ws = (char*)d_ws;
    float*  z      = (float*) (ws + 0);            // 16 MB
    float*  rst    = (float*) (ws + 16777216);     // 16 MB
    float*  zsrc   = (float*) (ws + 33554432);     // 256 KB
    float*  zdst   = (float*) (ws + 33816576);     // 256 KB
    int*    topk   = (int*)   (ws + 34078720);     // 40 KB
    float*  es_src = (float*) (ws + 34119680);     // 2 KB
    float*  es_dst = (float*) (ws + 34121728);     // 2 KB
    double* gstats = (double*)(ws + 34123776);     // 1 KB

    k1_pre<<<1537, 256, 0, stream>>>(data, emb, fc_w, fc_b, attn_w,
                                     es_src, es_dst, gstats,
                                     z, zsrc, zdst, topk);
    k3_attn<<<BB * 4, 256, 0, stream>>>(z, zsrc, zdst, es_src, es_dst, topk, emb,
                                        attn_b, rst, gstats);
    k5_out<<<4096, 256, 0, stream>>>(rst, gstats, gamma, beta, out_w, out_b, out);
}